// Round 4
// baseline (132.942 us; speedup 1.0000x reference)
//
#include <hip/hip_runtime.h>
#include <hip/hip_bf16.h>

#define HH 56
#define WW 56
#define CIN 64
#define COUT 64
#define BATCH 32
#define KK 9
#define HWP (HH*WW)      // 3136
#define NS 18            // K-steps of 32 (576/32)

typedef __attribute__((ext_vector_type(8))) short short8;
typedef __attribute__((ext_vector_type(4))) float float4v;

__device__ __forceinline__ unsigned short f2bf(float f) {
    union { float f; unsigned u; } v; v.f = f;
    unsigned r = v.u + 0x7FFFu + ((v.u >> 16) & 1u);
    return (unsigned short)(r >> 16);
}

// Prepack weight (COUT,CIN,3,3) fp32 -> bf16 A-fragment layout:
// apack[((mb*18 + s)*64 + lane)*8 + j] = bf16( w[o][c][k] )
//   o = mb*16 + (lane&15); c = (s&1)*32 + (lane>>4)*8 + j; k = s>>1
__global__ void prepack_weights(const float* __restrict__ w,
                                unsigned short* __restrict__ apack) {
    int e = blockIdx.x * 256 + threadIdx.x;      // 0 .. 36863
    int j = e & 7;
    int l = (e >> 3) & 63;
    int ss = e >> 9;                             // 0..71
    int mb = ss / 18;
    int s  = ss - mb * 18;
    int o = mb * 16 + (l & 15);
    int c = ((s & 1) << 5) + ((l >> 4) << 3) + j;
    int k = s >> 1;
    apack[e] = f2bf(w[(o * CIN + c) * KK + k]);
}

__global__ __launch_bounds__(256, 2) void dconv_kernel(
    const float* __restrict__ x, const int* __restrict__ sidx,
    const unsigned short* __restrict__ apack, float* __restrict__ out)
{
    // bf16 c-pair array: xs[c2][ls], c2=0..31 (c pair), ls = local src in 22x22 region
    __shared__ unsigned int xs[32 * 484];        // 61952 B
    __shared__ int lidxb[576];                   // per (p,k) LDS byte offset of gather src

    const int t    = threadIdx.x;
    const int lane = t & 63;
    const int wv   = t >> 6;                     // wave id = o-block (mb)
    const int bx   = blockIdx.x;                 // 0..48 pixel tile
    const int b    = blockIdx.y;                 // batch
    const int ti = bx / 7, tj = bx - (bx / 7) * 7;
    int r0 = ti * 8 - 7; if (r0 < 0) r0 = 0;
    int r1 = ti * 8 + 14; if (r1 > HH - 1) r1 = HH - 1;
    int c0 = tj * 8 - 7; if (c0 < 0) c0 = 0;
    int c1 = tj * 8 + 14; if (c1 > WW - 1) c1 = WW - 1;

    // ---- per-tile local gather offsets (byte offsets into a [22-stride] region) ----
    for (int e = t; e < 576; e += 256) {
        int p = e / 9, k = e - p * 9;
        int gi = ti * 8 + (p >> 3), gj = tj * 8 + (p & 7);
        int g = sidx[(gi * WW + gj) * KK + k];
        int si = g / WW, sj = g - si * WW;
        lidxb[e] = ((si - r0) * 22 + (sj - c0)) * 4;
    }

    // ---- A fragments: 18 K-steps, resident in registers ----
    short8 areg[NS];
    {
        const unsigned short* ap = apack + (wv * NS) * 512 + lane * 8;
        #pragma unroll
        for (int s = 0; s < NS; ++s)
            areg[s] = *(const short8*)(ap + s * 512);
    }

    // ---- stage x region into LDS as packed bf16 c-pairs ----
    const float* xb = x + (size_t)b * CIN * HWP;
    for (int e = t; e < 32 * 512; e += 256) {
        int c2 = e >> 9, ls = e & 511;
        if (ls < 484) {
            int lsr = ls / 22;
            int si = r0 + lsr, sj = c0 + (ls - lsr * 22);
            if (si <= r1 && sj <= c1) {
                int g = si * WW + sj;
                float f0 = xb[(2 * c2) * HWP + g];
                float f1 = xb[(2 * c2 + 1) * HWP + g];
                xs[c2 * 484 + ls] =
                    (unsigned)f2bf(f0) | ((unsigned)f2bf(f1) << 16);
            }
        }
    }
    __syncthreads();

    // ---- main MFMA loop ----
    float4v zero = {0.f, 0.f, 0.f, 0.f};
    float4v acc[4] = {zero, zero, zero, zero};
    const int col  = lane & 15;
    const int krow = lane >> 4;                  // 0..3
    const char* xsb = (const char*)xs;

    #pragma unroll
    for (int k = 0; k < 9; ++k) {
        #pragma unroll
        for (int nt = 0; nt < 4; ++nt) {
            int p  = nt * 16 + col;
            int lb = lidxb[p * 9 + k];
            #pragma unroll
            for (int sh = 0; sh < 2; ++sh) {
                int s = 2 * k + sh;
                // c2 base = sh*16 + krow*4 ; per-c2 stride = 484*4 = 1936 B
                const char* ba = xsb + (sh * 16 + krow * 4) * 1936 + lb;
                union { int i[4]; short8 s8; } bu;
                bu.i[0] = *(const int*)(ba);
                bu.i[1] = *(const int*)(ba + 1936);
                bu.i[2] = *(const int*)(ba + 3872);
                bu.i[3] = *(const int*)(ba + 5808);
                acc[nt] = __builtin_amdgcn_mfma_f32_16x16x32_bf16(
                    areg[s], bu.s8, acc[nt], 0, 0, 0);
            }
        }
    }

    // ---- epilogue: D[row][col] -> out[b][o][pixel] ----
    float* ob = out + ((size_t)b * COUT + wv * 16) * HWP;
    #pragma unroll
    for (int nt = 0; nt < 4; ++nt) {
        int p = nt * 16 + col;
        int g = (ti * 8 + (p >> 3)) * WW + tj * 8 + (p & 7);
        #pragma unroll
        for (int r = 0; r < 4; ++r) {
            ob[(krow * 4 + r) * HWP + g] = acc[nt][r];
        }
    }
}

extern "C" void kernel_launch(void* const* d_in, const int* in_sizes, int n_in,
                              void* d_out, int out_size, void* d_ws, size_t ws_size,
                              hipStream_t stream) {
    const float* x    = (const float*)d_in[0];
    const float* w    = (const float*)d_in[1];
    const int*   sidx = (const int*)d_in[2];
    float* out = (float*)d_out;
    unsigned short* apack = (unsigned short*)d_ws;   // 36864 * 2 B = 72 KiB

    prepack_weights<<<144, 256, 0, stream>>>(w, apack);
    dim3 grid(49, BATCH);
    dconv_kernel<<<grid, 256, 0, stream>>>(x, sidx, apack, out);
}

// Round 5
// 128.519 us; speedup vs baseline: 1.0344x; 1.0344x over previous
//
#include <hip/hip_runtime.h>
#include <hip/hip_bf16.h>

#define HH 56
#define WW 56
#define CIN 64
#define COUT 64
#define BATCH 32
#define KK 9
#define HWP (HH*WW)      // 3136
#define NS 18            // K-steps of 32 (576/32)
#define XSW 33           // LDS words per ls entry (32 c2 + 1 pad)

typedef __attribute__((ext_vector_type(8))) short short8;
typedef __attribute__((ext_vector_type(4))) float float4v;

__device__ __forceinline__ unsigned short f2bf(float f) {
    union { float f; unsigned u; } v; v.f = f;
    unsigned r = v.u + 0x7FFFu + ((v.u >> 16) & 1u);
    return (unsigned short)(r >> 16);
}

// Prepack weight (COUT,CIN,3,3) fp32 -> bf16 A-fragment layout:
// apack[((mb*18 + s)*64 + lane)*8 + j] = bf16( w[o][c][k] )
//   o = mb*16 + (lane&15); c = (s&1)*32 + (lane>>4)*8 + j; k = s>>1
__global__ void prepack_weights(const float* __restrict__ w,
                                unsigned short* __restrict__ apack) {
    int e = blockIdx.x * 256 + threadIdx.x;      // 0 .. 36863
    int j = e & 7;
    int l = (e >> 3) & 63;
    int ss = e >> 9;                             // 0..71
    int mb = ss / 18;
    int s  = ss - mb * 18;
    int o = mb * 16 + (l & 15);
    int c = ((s & 1) << 5) + ((l >> 4) << 3) + j;
    int k = s >> 1;
    apack[e] = f2bf(w[(o * CIN + c) * KK + k]);
}

__global__ __launch_bounds__(256, 2) void dconv_kernel(
    const float* __restrict__ x, const int* __restrict__ sidx,
    const unsigned short* __restrict__ apack, float* __restrict__ out)
{
    // xs[ls][c2]: ls = local src in 22x22 region, c2 = channel pair (32).
    // stride 33 words -> bank (ls + c2) % 32, fragment words contiguous.
    __shared__ unsigned int xs[484 * XSW];       // 63,888 B

    const int t    = threadIdx.x;
    const int lane = t & 63;
    const int wv   = t >> 6;
    const int mbp  = wv >> 1;                    // o-block pair: mb = 2*mbp + m
    const int ntp  = wv & 1;                     // pixel-tile pair: nt = 2*ntp + nn
    const int col  = lane & 15;
    const int krow = lane >> 4;                  // 0..3
    const int bx   = blockIdx.x;
    const int b    = blockIdx.y;
    const int ti = bx / 7, tj = bx - (bx / 7) * 7;
    int r0 = ti * 8 - 7; if (r0 < 0) r0 = 0;
    int r1 = ti * 8 + 14; if (r1 > HH - 1) r1 = HH - 1;
    int c0 = tj * 8 - 7; if (c0 < 0) c0 = 0;
    int c1 = tj * 8 + 14; if (c1 > WW - 1) c1 = WW - 1;

    // ---- per-lane gather byte offsets, in registers (sidx is L2-resident) ----
    int lb[2][KK];
    #pragma unroll
    for (int nn = 0; nn < 2; ++nn) {
        int p  = (ntp * 2 + nn) * 16 + col;
        int gi = ti * 8 + (p >> 3), gj = tj * 8 + (p & 7);
        const int* sp = sidx + (gi * WW + gj) * KK;
        #pragma unroll
        for (int k = 0; k < KK; ++k) {
            int g  = sp[k];
            int si = g / WW, sj = g - si * WW;
            lb[nn][k] = ((si - r0) * 22 + (sj - c0)) * (XSW * 4);
        }
    }

    // ---- A fragments: 2 o-blocks x 18 K-steps, resident in registers ----
    short8 areg[2][NS];
    #pragma unroll
    for (int m = 0; m < 2; ++m) {
        const unsigned short* ap = apack + ((mbp * 2 + m) * NS) * 512 + lane * 8;
        #pragma unroll
        for (int s = 0; s < NS; ++s)
            areg[m][s] = *(const short8*)(ap + s * 512);
    }

    // ---- stage x region into LDS as packed bf16 c-pairs, [ls][c2] ----
    const float* xb = x + (size_t)b * CIN * HWP;
    for (int e = t; e < 32 * 512; e += 256) {
        int c2 = e >> 9, ls = e & 511;
        if (ls < 484) {
            int lsr = ls / 22;
            int si = r0 + lsr, sj = c0 + (ls - lsr * 22);
            if (si <= r1 && sj <= c1) {
                int g = si * WW + sj;
                float f0 = xb[(2 * c2) * HWP + g];
                float f1 = xb[(2 * c2 + 1) * HWP + g];
                xs[ls * XSW + c2] =
                    (unsigned)f2bf(f0) | ((unsigned)f2bf(f1) << 16);
            }
        }
    }
    __syncthreads();

    // ---- main MFMA loop: per (k,nn): 8 contiguous-word LDS loads + 4 MFMA ----
    float4v zero = {0.f, 0.f, 0.f, 0.f};
    float4v acc[2][2] = {{zero, zero}, {zero, zero}};
    const char* xsb = (const char*)xs + krow * 16;

    #pragma unroll
    for (int k = 0; k < KK; ++k) {
        #pragma unroll
        for (int nn = 0; nn < 2; ++nn) {
            const char* ba = xsb + lb[nn][k];
            union { int i[4]; short8 s8; } b0, b1;
            #pragma unroll
            for (int w = 0; w < 4; ++w) {
                b0.i[w] = *(const int*)(ba + w * 4);        // c2 = krow*4 + w
                b1.i[w] = *(const int*)(ba + 64 + w * 4);   // c2 = 16 + krow*4 + w
            }
            acc[0][nn] = __builtin_amdgcn_mfma_f32_16x16x32_bf16(
                areg[0][2 * k], b0.s8, acc[0][nn], 0, 0, 0);
            acc[1][nn] = __builtin_amdgcn_mfma_f32_16x16x32_bf16(
                areg[1][2 * k], b0.s8, acc[1][nn], 0, 0, 0);
            acc[0][nn] = __builtin_amdgcn_mfma_f32_16x16x32_bf16(
                areg[0][2 * k + 1], b1.s8, acc[0][nn], 0, 0, 0);
            acc[1][nn] = __builtin_amdgcn_mfma_f32_16x16x32_bf16(
                areg[1][2 * k + 1], b1.s8, acc[1][nn], 0, 0, 0);
        }
    }

    // ---- epilogue: D[row][col] -> out[b][o][pixel] ----
    float* ob = out + ((size_t)b * COUT + mbp * 32) * HWP;
    #pragma unroll
    for (int m = 0; m < 2; ++m) {
        #pragma unroll
        for (int nn = 0; nn < 2; ++nn) {
            int p = (ntp * 2 + nn) * 16 + col;
            int g = (ti * 8 + (p >> 3)) * WW + tj * 8 + (p & 7);
            #pragma unroll
            for (int r = 0; r < 4; ++r) {
                ob[(m * 16 + krow * 4 + r) * HWP + g] = acc[m][nn][r];
            }
        }
    }
}

extern "C" void kernel_launch(void* const* d_in, const int* in_sizes, int n_in,
                              void* d_out, int out_size, void* d_ws, size_t ws_size,
                              hipStream_t stream) {
    const float* x    = (const float*)d_in[0];
    const float* w    = (const float*)d_in[1];
    const int*   sidx = (const int*)d_in[2];
    float* out = (float*)d_out;
    unsigned short* apack = (unsigned short*)d_ws;   // 36864 * 2 B = 72 KiB

    prepack_weights<<<144, 256, 0, stream>>>(w, apack);
    dim3 grid(49, BATCH);
    dconv_kernel<<<grid, 256, 0, stream>>>(x, sidx, apack, out);
}

// Round 6
// 43.023 us; speedup vs baseline: 3.0900x; 2.9872x over previous
//
#include <hip/hip_runtime.h>
#include <hip/hip_bf16.h>

#define HH 56
#define WW 56
#define CIN 64
#define COUT 64
#define BATCH 32
#define KK 9
#define HWP (HH*WW)      // 3136
#define NS 18            // K-steps of 32 (576/32)
#define NTILE 49
#define NBLK (NTILE*BATCH)   // 1568 = 8 * 196
#define XT_OFF 73728         // bytes: apack (72 KiB) precedes xt in d_ws
#define XSW 33               // fallback LDS stride

typedef __attribute__((ext_vector_type(8))) short short8;
typedef __attribute__((ext_vector_type(4))) float float4v;
typedef __attribute__((ext_vector_type(4))) unsigned int uint4v;

__device__ __forceinline__ unsigned short f2bf(float f) {
    union { float f; unsigned u; } v; v.f = f;
    unsigned r = v.u + 0x7FFFu + ((v.u >> 16) & 1u);
    return (unsigned short)(r >> 16);
}

// Prepack weight (COUT,CIN,3,3) fp32 -> bf16 A-fragment layout:
// o = mb*16 + (lane&15); c = (s&1)*32 + (lane>>4)*8 + j; k = s>>1
__global__ void prepack_weights(const float* __restrict__ w,
                                unsigned short* __restrict__ apack) {
    int e = blockIdx.x * 256 + threadIdx.x;      // 0 .. 36863
    int j = e & 7;
    int l = (e >> 3) & 63;
    int ss = e >> 9;
    int mb = ss / 18;
    int s  = ss - mb * 18;
    int o = mb * 16 + (l & 15);
    int c = ((s & 1) << 5) + ((l >> 4) << 3) + j;
    int k = s >> 1;
    apack[e] = f2bf(w[(o * CIN + c) * KK + k]);
}

// x (B,CIN,H,W) f32 -> xt[b][hw][c2] packed bf16 pairs (128 B per pixel)
__global__ __launch_bounds__(256) void transpose_x(const float* __restrict__ x,
                                                   unsigned int* __restrict__ xt) {
    __shared__ unsigned int tl[32 * 257];        // [c2][hw] pad-257
    int b   = blockIdx.y;
    int hw0 = blockIdx.x * 256;
    int t   = threadIdx.x;
    int hw  = hw0 + t;
    const float* xb = x + (size_t)b * CIN * HWP;
    #pragma unroll
    for (int c2 = 0; c2 < 32; ++c2) {
        unsigned v = 0;
        if (hw < HWP) {
            float f0 = xb[(2 * c2) * HWP + hw];
            float f1 = xb[(2 * c2 + 1) * HWP + hw];
            v = (unsigned)f2bf(f0) | ((unsigned)f2bf(f1) << 16);
        }
        tl[c2 * 257 + t] = v;
    }
    __syncthreads();
    unsigned int* xtb = xt + ((size_t)b * HWP + hw0) * 32;
    for (int i = 0; i < 8; ++i) {
        int hwl = i * 32 + (t >> 3);
        int c2q = t & 7;
        if (hw0 + hwl < HWP) {
            uint4v u;
            #pragma unroll
            for (int w = 0; w < 4; ++w)
                u[w] = tl[(c2q * 4 + w) * 257 + hwl];
            *(uint4v*)(xtb + (size_t)hwl * 32 + c2q * 4) = u;
        }
    }
}

// ---------------- main kernel (xt path) ----------------
__global__ __launch_bounds__(256, 2) void dconv_main(
    const unsigned int* __restrict__ xt, const int* __restrict__ sidx,
    const unsigned short* __restrict__ apack, float* __restrict__ out)
{
    // linear [ls][c2] rows of 128 B; source-side XOR swizzle quad^=(ls&7)
    __shared__ unsigned int xs[488 * 32];        // 62,464 B

    const int t    = threadIdx.x;
    const int lane = t & 63;
    const int wv   = t >> 6;
    const int mbp  = wv >> 1;
    const int ntp  = wv & 1;
    const int col  = lane & 15;
    const int krow = lane >> 4;

    // XCD-aware bijective swizzle: XCD k gets orig range [k*196,(k+1)*196)
    int bid  = blockIdx.x;
    int orig = (bid & 7) * 196 + (bid >> 3);
    int b    = orig / NTILE;
    int bx   = orig - b * NTILE;
    int ti = bx / 7, tj = bx - (bx / 7) * 7;
    int r0 = ti * 8 - 7; if (r0 < 0) r0 = 0;
    int c0 = tj * 8 - 7; if (c0 < 0) c0 = 0;

    // ---- staging: issue async global->LDS FIRST ----
    const unsigned int* xtb = xt + (size_t)b * HWP * 32;
    for (int grp = wv; grp < 61; grp += 4) {
        int ls  = grp * 8 + (lane >> 3);
        int lsr = ls / 22;
        int lsc = ls - lsr * 22;
        int si = r0 + lsr; if (si > HH - 1) si = HH - 1;
        int sj = c0 + lsc; if (sj > WW - 1) sj = WW - 1;
        const unsigned int* src =
            xtb + (size_t)(si * WW + sj) * 32 + (((lane & 7) ^ (lane >> 3)) << 2);
        __builtin_amdgcn_global_load_lds(
            (const __attribute__((address_space(1))) unsigned int*)src,
            (__attribute__((address_space(3))) unsigned int*)(xs + grp * 256),
            16, 0, 0);
    }

    // ---- per-lane gather byte offsets (incl. read-side swizzle) ----
    int lb[2][KK];
    #pragma unroll
    for (int nn = 0; nn < 2; ++nn) {
        int p  = (ntp * 2 + nn) * 16 + col;
        int gi = ti * 8 + (p >> 3), gj = tj * 8 + (p & 7);
        const int* sp = sidx + (gi * WW + gj) * KK;
        #pragma unroll
        for (int k = 0; k < KK; ++k) {
            int g  = sp[k];
            int si = g / WW, sj = g - si * WW;
            int row = (si - r0) * 22 + (sj - c0);
            lb[nn][k] = row * 128 + ((krow ^ (row & 7)) << 4);
        }
    }

    // ---- A fragments: 2 o-blocks x 18 K-steps in registers ----
    short8 areg[2][NS];
    #pragma unroll
    for (int m = 0; m < 2; ++m) {
        const unsigned short* ap = apack + ((mbp * 2 + m) * NS) * 512 + lane * 8;
        #pragma unroll
        for (int s = 0; s < NS; ++s)
            areg[m][s] = *(const short8*)(ap + s * 512);
    }
    __syncthreads();

    // ---- main MFMA loop ----
    float4v zero = {0.f, 0.f, 0.f, 0.f};
    float4v acc[2][2] = {{zero, zero}, {zero, zero}};
    const char* xsb = (const char*)xs;

    #pragma unroll
    for (int k = 0; k < KK; ++k) {
        #pragma unroll
        for (int nn = 0; nn < 2; ++nn) {
            int o0 = lb[nn][k];
            short8 bv0 = *(const short8*)(xsb + o0);
            short8 bv1 = *(const short8*)(xsb + (o0 ^ 64));
            acc[0][nn] = __builtin_amdgcn_mfma_f32_16x16x32_bf16(
                areg[0][2 * k], bv0, acc[0][nn], 0, 0, 0);
            acc[1][nn] = __builtin_amdgcn_mfma_f32_16x16x32_bf16(
                areg[1][2 * k], bv0, acc[1][nn], 0, 0, 0);
            acc[0][nn] = __builtin_amdgcn_mfma_f32_16x16x32_bf16(
                areg[0][2 * k + 1], bv1, acc[0][nn], 0, 0, 0);
            acc[1][nn] = __builtin_amdgcn_mfma_f32_16x16x32_bf16(
                areg[1][2 * k + 1], bv1, acc[1][nn], 0, 0, 0);
        }
    }

    // ---- epilogue ----
    float* ob = out + ((size_t)b * COUT + mbp * 32) * HWP;
    #pragma unroll
    for (int m = 0; m < 2; ++m) {
        #pragma unroll
        for (int nn = 0; nn < 2; ++nn) {
            int p = (ntp * 2 + nn) * 16 + col;
            int g = (ti * 8 + (p >> 3)) * WW + tj * 8 + (p & 7);
            #pragma unroll
            for (int r = 0; r < 4; ++r)
                ob[(m * 16 + krow * 4 + r) * HWP + g] = acc[m][nn][r];
        }
    }
}

// ---------------- fallback (round-5 path, if ws too small) ----------------
__global__ __launch_bounds__(256, 2) void dconv_fb(
    const float* __restrict__ x, const int* __restrict__ sidx,
    const unsigned short* __restrict__ apack, float* __restrict__ out)
{
    __shared__ unsigned int xs[484 * XSW];

    const int t    = threadIdx.x;
    const int lane = t & 63;
    const int wv   = t >> 6;
    const int mbp  = wv >> 1;
    const int ntp  = wv & 1;
    const int col  = lane & 15;
    const int krow = lane >> 4;
    const int bx   = blockIdx.x;
    const int b    = blockIdx.y;
    const int ti = bx / 7, tj = bx - (bx / 7) * 7;
    int r0 = ti * 8 - 7; if (r0 < 0) r0 = 0;
    int r1 = ti * 8 + 14; if (r1 > HH - 1) r1 = HH - 1;
    int c0 = tj * 8 - 7; if (c0 < 0) c0 = 0;
    int c1 = tj * 8 + 14; if (c1 > WW - 1) c1 = WW - 1;

    int lb[2][KK];
    #pragma unroll
    for (int nn = 0; nn < 2; ++nn) {
        int p  = (ntp * 2 + nn) * 16 + col;
        int gi = ti * 8 + (p >> 3), gj = tj * 8 + (p & 7);
        const int* sp = sidx + (gi * WW + gj) * KK;
        #pragma unroll
        for (int k = 0; k < KK; ++k) {
            int g  = sp[k];
            int si = g / WW, sj = g - si * WW;
            lb[nn][k] = ((si - r0) * 22 + (sj - c0)) * (XSW * 4);
        }
    }

    short8 areg[2][NS];
    #pragma unroll
    for (int m = 0; m < 2; ++m) {
        const unsigned short* ap = apack + ((mbp * 2 + m) * NS) * 512 + lane * 8;
        #pragma unroll
        for (int s = 0; s < NS; ++s)
            areg[m][s] = *(const short8*)(ap + s * 512);
    }

    const float* xb = x + (size_t)b * CIN * HWP;
    for (int e = t; e < 32 * 512; e += 256) {
        int c2 = e >> 9, ls = e & 511;
        if (ls < 484) {
            int lsr = ls / 22;
            int si = r0 + lsr, sj = c0 + (ls - lsr * 22);
            if (si <= r1 && sj <= c1) {
                int g = si * WW + sj;
                float f0 = xb[(2 * c2) * HWP + g];
                float f1 = xb[(2 * c2 + 1) * HWP + g];
                xs[ls * XSW + c2] =
                    (unsigned)f2bf(f0) | ((unsigned)f2bf(f1) << 16);
            }
        }
    }
    __syncthreads();

    float4v zero = {0.f, 0.f, 0.f, 0.f};
    float4v acc[2][2] = {{zero, zero}, {zero, zero}};
    const char* xsb = (const char*)xs + krow * 16;

    #pragma unroll
    for (int k = 0; k < KK; ++k) {
        #pragma unroll
        for (int nn = 0; nn < 2; ++nn) {
            const char* ba = xsb + lb[nn][k];
            union { int i[4]; short8 s8; } b0, b1;
            #pragma unroll
            for (int w = 0; w < 4; ++w) {
                b0.i[w] = *(const int*)(ba + w * 4);
                b1.i[w] = *(const int*)(ba + 64 + w * 4);
            }
            acc[0][nn] = __builtin_amdgcn_mfma_f32_16x16x32_bf16(
                areg[0][2 * k], b0.s8, acc[0][nn], 0, 0, 0);
            acc[1][nn] = __builtin_amdgcn_mfma_f32_16x16x32_bf16(
                areg[1][2 * k], b0.s8, acc[1][nn], 0, 0, 0);
            acc[0][nn] = __builtin_amdgcn_mfma_f32_16x16x32_bf16(
                areg[0][2 * k + 1], b1.s8, acc[0][nn], 0, 0, 0);
            acc[1][nn] = __builtin_amdgcn_mfma_f32_16x16x32_bf16(
                areg[1][2 * k + 1], b1.s8, acc[1][nn], 0, 0, 0);
        }
    }

    float* ob = out + ((size_t)b * COUT + mbp * 32) * HWP;
    #pragma unroll
    for (int m = 0; m < 2; ++m) {
        #pragma unroll
        for (int nn = 0; nn < 2; ++nn) {
            int p = (ntp * 2 + nn) * 16 + col;
            int g = (ti * 8 + (p >> 3)) * WW + tj * 8 + (p & 7);
            #pragma unroll
            for (int r = 0; r < 4; ++r)
                ob[(m * 16 + krow * 4 + r) * HWP + g] = acc[m][nn][r];
        }
    }
}

extern "C" void kernel_launch(void* const* d_in, const int* in_sizes, int n_in,
                              void* d_out, int out_size, void* d_ws, size_t ws_size,
                              hipStream_t stream) {
    const float* x    = (const float*)d_in[0];
    const float* w    = (const float*)d_in[1];
    const int*   sidx = (const int*)d_in[2];
    float* out = (float*)d_out;
    unsigned short* apack = (unsigned short*)d_ws;                       // 72 KiB
    unsigned int*   xt    = (unsigned int*)((char*)d_ws + XT_OFF);       // 12.84 MB

    size_t need = (size_t)XT_OFF + (size_t)BATCH * HWP * 128;
    prepack_weights<<<144, 256, 0, stream>>>(w, apack);
    if (ws_size >= need) {
        transpose_x<<<dim3(13, BATCH), 256, 0, stream>>>(x, xt);
        dconv_main<<<NBLK, 256, 0, stream>>>(xt, sidx, apack, out);
    } else {
        dim3 grid(NTILE, BATCH);
        dconv_fb<<<grid, 256, 0, stream>>>(x, sidx, apack, out);
    }
}